// Round 6
// baseline (254.231 us; speedup 1.0000x reference)
//
#include <hip/hip_runtime.h>
#include <hip/hip_fp16.h>
#include <cstdint>

typedef unsigned short u16;
typedef __attribute__((ext_vector_type(8))) short short8;
typedef __attribute__((ext_vector_type(4))) float float4v;

#define NTOK 8192
#define HDIM 1024
#define NEXP 8
#define TM 128
#define TN 128
#define BK 32
#define KSPL 2                   // K-split factor (blockIdx.z)
#define NITER (HDIM / BK / KSPL) // 16 k-tiles per block
#define LA_N (TM * BK)           // one A buffer: 4096 u16 = 8 KB
#define LB_N (TN * BK)
#define MAXT 136   // max m-tiles over all experts: 16384/128 + 8 rounding partials
#define WBLK 8192  // prep: W-transpose blocks (32 x 32 x 8)
#define RBLK 2048  // prep: router blocks (4 tokens each)

__device__ __forceinline__ u16 f2bf(float f) {
    union { float f; uint32_t u; } v; v.f = f;
    uint32_t u = v.u;
    return (u16)((u + 0x7FFFu + ((u >> 16) & 1u)) >> 16);
}

// async global->LDS, 16B per lane; LDS dest = wave-uniform base + lane*16
__device__ __forceinline__ void gll16(const u16* g, u16* l) {
    __builtin_amdgcn_global_load_lds(
        (const __attribute__((address_space(1))) uint32_t*)g,
        (__attribute__((address_space(3))) uint32_t*)l,
        16, 0, 0);
}

// ------- fused prep: out-zeroing AND W transpose+quantize AND router AND ctrl zeroing --
__global__ __launch_bounds__(256) void prep(const float* __restrict__ x,
                                            const float* __restrict__ rw,
                                            const float* __restrict__ ew,
                                            u16* __restrict__ x_bf,
                                            u16* __restrict__ w_bf,
                                            float* __restrict__ wt0,
                                            float* __restrict__ wt1,
                                            float* __restrict__ biasv,
                                            int* __restrict__ sel,
                                            int* __restrict__ ctrl,
                                            float* __restrict__ out) {
    if (blockIdx.x == 0 && threadIdx.x < 132) ctrl[threadIdx.x] = 0;  // counts[8x16] + done

    if (blockIdx.x < WBLK) {
        // zero the atomic-accumulated output: 8192 blocks x 256 thr x float4 = 8M floats
        {
            const size_t zi = ((size_t)blockIdx.x * 256 + threadIdx.x) * 4;
            float4 z; z.x = 0.f; z.y = 0.f; z.z = 0.f; z.w = 0.f;
            *(float4*)(out + zi) = z;
        }
        __shared__ float tile[32][33];
        const int bid = blockIdx.x;
        const int e  = bid >> 10;
        const int k0 = (bid & 31) * 32;
        const int n0 = ((bid >> 5) & 31) * 32;
        const int r = threadIdx.x >> 3;        // 0..31
        const int c = (threadIdx.x & 7) * 4;   // 0,4,...,28
        const float4 v = *(const float4*)(ew + ((size_t)e << 20) + (size_t)(k0 + r) * HDIM + n0 + c);
        tile[r][c] = v.x; tile[r][c+1] = v.y; tile[r][c+2] = v.z; tile[r][c+3] = v.w;
        __syncthreads();
        ushort4 o;
        o.x = f2bf(tile[c][r]); o.y = f2bf(tile[c+1][r]);
        o.z = f2bf(tile[c+2][r]); o.w = f2bf(tile[c+3][r]);
        *(ushort4*)(w_bf + ((size_t)e << 20) + (size_t)(n0 + r) * HDIM + k0 + c) = o;
    } else {
        const int wv = threadIdx.x >> 6;
        const int l  = threadIdx.x & 63;
        const int n  = (blockIdx.x - WBLK) * 4 + wv;  // one wave per token
        const float4* xr = (const float4*)(x + (size_t)n * HDIM);
        ushort4* xo = (ushort4*)(x_bf + (size_t)n * HDIM);

        float4 xv[4];
#pragma unroll
        for (int t = 0; t < 4; t++) {
            xv[t] = xr[t * 64 + l];
            ushort4 p;
            p.x = f2bf(xv[t].x); p.y = f2bf(xv[t].y);
            p.z = f2bf(xv[t].z); p.w = f2bf(xv[t].w);
            xo[t * 64 + l] = p;
        }

        float logits[NEXP];
#pragma unroll
        for (int e = 0; e < NEXP; e++) {
            const float4* rwe = (const float4*)(rw + e * HDIM);
            float acc = 0.f;
#pragma unroll
            for (int t = 0; t < 4; t++) {
                const float4 r = rwe[t * 64 + l];
                acc += xv[t].x * r.x + xv[t].y * r.y + xv[t].z * r.z + xv[t].w * r.w;
            }
#pragma unroll
            for (int s = 32; s > 0; s >>= 1) acc += __shfl_xor(acc, s, 64);
            logits[e] = acc;
        }

        if (l == 0) {
            float mx = logits[0];
#pragma unroll
            for (int e = 1; e < NEXP; e++) mx = fmaxf(mx, logits[e]);
            float p[NEXP]; float sum = 0.f;
#pragma unroll
            for (int e = 0; e < NEXP; e++) { p[e] = expf(logits[e] - mx); sum += p[e]; }
            const float inv = 1.f / sum;
#pragma unroll
            for (int e = 0; e < NEXP; e++) p[e] *= inv;
            int e0 = 0;
#pragma unroll
            for (int e = 1; e < NEXP; e++) if (p[e] > p[e0]) e0 = e;  // ties -> lowest idx
            int e1 = (e0 == 0) ? 1 : 0;
#pragma unroll
            for (int e = 0; e < NEXP; e++) if (e != e0 && p[e] > p[e1]) e1 = e;
            const float p0 = p[e0], p1 = p[e1];
            const float wsum = p0 + p1 + 1e-6f;
            const float w0 = p0 / wsum, w1 = p1 / wsum;
            wt0[n] = w0; wt1[n] = w1;
            biasv[n] = w0 * p0 + w1 * p1;
            sel[n] = e0 | (e1 << 8);
        }
    }
}

// ---------------- list build + fused tile planning (last block plans) ------------------
__global__ __launch_bounds__(256) void build_lists(const int* __restrict__ sel,
                                                   int* __restrict__ lists,
                                                   int* __restrict__ ctrl,
                                                   int* __restrict__ tmap) {
    const int n  = blockIdx.x * 256 + threadIdx.x;
    const int wv = threadIdx.x >> 6;
    const int l  = threadIdx.x & 63;
    const int s  = sel[n];
    const int e0 = s & 0xFF, e1 = s >> 8;
    __shared__ int wcnt[NEXP][4];
    __shared__ int ebase[NEXP];
    int pf0 = 0, pf1 = 0;
    const unsigned long long ltmask = (1ULL << l) - 1ULL;
#pragma unroll
    for (int e = 0; e < NEXP; e++) {
        const int slot = (e0 == e) ? 0 : ((e1 == e) ? 1 : -1);
        const unsigned long long bal = __ballot(slot >= 0);
        const int pf = __popcll(bal & ltmask);
        if (slot == 0) pf0 = pf;
        if (slot == 1) pf1 = pf;
        if (l == 0) wcnt[e][wv] = __popcll(bal);
    }
    __syncthreads();
    if (threadIdx.x < NEXP) {
        const int e = threadIdx.x;
        const int tot = wcnt[e][0] + wcnt[e][1] + wcnt[e][2] + wcnt[e][3];
        ebase[e] = atomicAdd(&ctrl[e * 16], tot);   // counters 64B apart
    }
    __syncthreads();
    int off0 = ebase[e0], off1 = ebase[e1];
#pragma unroll
    for (int i = 0; i < 4; i++) {
        off0 += (i < wv) ? wcnt[e0][i] : 0;
        off1 += (i < wv) ? wcnt[e1][i] : 0;
    }
    lists[e0 * NTOK + off0 + pf0] = n;              // slot 0
    lists[e1 * NTOK + off1 + pf1] = n | 0x10000;    // slot 1

    // ---- last block to finish plans the dense tile map ----
    __shared__ int lastflag;
    __threadfence();
    if (threadIdx.x == 0) lastflag = (atomicAdd(&ctrl[128], 1) == (int)gridDim.x - 1);
    __syncthreads();
    if (lastflag) {
        __shared__ int tbase[NEXP + 1];
        if (threadIdx.x == 0) {
            int acc = 0;
            for (int e = 0; e < NEXP; e++) {
                tbase[e] = acc;
                acc += (atomicAdd(&ctrl[e * 16], 0) + TM - 1) / TM;  // device-scope read
            }
            tbase[NEXP] = acc;
        }
        __syncthreads();
        for (int i = threadIdx.x; i < MAXT; i += 256) {
            int v = -1;
#pragma unroll
            for (int e = 0; e < NEXP; e++)
                if (i >= tbase[e] && i < tbase[e + 1]) v = (e << 16) | (i - tbase[e]);
            tmap[i] = v;
        }
    }
}

// ------- grouped GEMM: 128x128, 4 waves of 64x64, reg-dbuf pipeline, K-split x2 -------
// R3 structure verbatim (best measured) + blockIdx.z K-split (K=512/block, NITER=16)
// + fp32 atomicAdd epilogue into out (no staging buffers, no combine kernel).
// 3 blocks/CU (LDS 50 KB, __launch_bounds__(256,3)).
// Register double-buffer of fragments; counted lgkmcnt(8) so MFMA never waits on the
// just-issued ds_reads; sched_barrier after waits (rule 18); full unroll keeps indices
// compile-time.
__global__ __launch_bounds__(256, 3) void moe_gemm(const u16* __restrict__ x_bf,
                                                   const u16* __restrict__ wt_bf,
                                                   const int* __restrict__ lists,
                                                   const int* __restrict__ ctrl,
                                                   const int* __restrict__ tmap,
                                                   const float* __restrict__ wt0,
                                                   const float* __restrict__ wt1,
                                                   const float* __restrict__ biasv,
                                                   float* __restrict__ out) {
    const int ent = tmap[blockIdx.x];
    if (ent < 0) return;
    const int e = ent >> 16;
    const int tile_m = (ent & 0xFFFF) * TM;
    const int cnt = ctrl[e * 16];
    const int tn = blockIdx.y * TN;
    const int kz = blockIdx.z * (HDIM / KSPL);   // 0 or 512 (u16 elements)

    __shared__ u16 lA[3 * LA_N];   // 24 KB
    __shared__ u16 lB[3 * LB_N];   // 24 KB
    __shared__ int   toks[TM];
    __shared__ float wgt[TM];
    __shared__ float bia[TM];

    const int t  = threadIdx.x;
    const int wv = t >> 6;
    const int l  = t & 63;

    if (t < TM) {
        const int idx = tile_m + t;
        int tok = 0; float w = 0.f, b = 0.f;
        if (idx < cnt) {
            const int entry = lists[e * NTOK + idx];
            tok = entry & 0xFFFF;
            const int sl = entry >> 16;
            w = sl ? wt1[tok] : wt0[tok];
            b = (sl || blockIdx.z) ? 0.f : biasv[tok];   // bias exactly once per token
        }
        toks[t] = tok; wgt[t] = w; bia[t] = b;
    }
    __syncthreads();

    // staging: slot s (16B) -> row = s>>2, phys-chunk pc = s&3, logical chunk
    // c = pc ^ ((row>>1)&3). A: 512 slots (2 wave-loads/wave), B same.
    const u16* gA[2]; const u16* gB[2]; int dAB[2];
#pragma unroll
    for (int i = 0; i < 2; i++) {
        const int slot = (i * 4 + wv) * 64 + l;
        const int row  = slot >> 2;
        const int c    = (slot & 3) ^ ((row >> 1) & 3);
        gA[i] = x_bf + (size_t)toks[row] * HDIM + kz + c * 8;
        gB[i] = wt_bf + ((size_t)e << 20) + (size_t)(tn + row) * HDIM + kz + c * 8;
        dAB[i] = (i * 4 + wv) * 512;                 // wave-uniform u16 offset in buffer
    }

    // fragment read offsets (swizzled, loop-invariant); wave -> 64x64 at (wm, wn)
    const int wm = (wv & 1) * 64;
    const int wn = (wv >> 1) * 64;
    const int fm = l & 15;
    const int fq = l >> 4;     // 0..3 (k-chunk)
    int aoff[4], boff[4];
#pragma unroll
    for (int i = 0; i < 4; i++) {
        const int ra = wm + i * 16 + fm;
        const int rb = wn + i * 16 + fm;
        aoff[i] = ra * BK + ((fq ^ ((ra >> 1) & 3)) * 8);
        boff[i] = rb * BK + ((fq ^ ((rb >> 1) & 3)) * 8);
    }

    float4v acc[4][4];
#pragma unroll
    for (int i = 0; i < 4; i++)
#pragma unroll
        for (int j = 0; j < 4; j++) { float4v z = {0.f, 0.f, 0.f, 0.f}; acc[i][j] = z; }

    short8 afr[2][4], bfr[2][4];   // register double-buffer of fragments

    // prologue: stage tiles 0,1,2 into buffers 0,1,2 (12 loads in flight)
#pragma unroll
    for (int tk = 0; tk < 3; tk++) {
#pragma unroll
        for (int i = 0; i < 2; i++) {
            gll16(gA[i] + tk * BK, lA + tk * LA_N + dAB[i]);
            gll16(gB[i] + tk * BK, lB + tk * LB_N + dAB[i]);
        }
    }
    // tile 0 landed (8 younger loads stay in flight)
    asm volatile("s_waitcnt vmcnt(8)\n\ts_barrier" ::: "memory");
    // read frags[0] into set 0
#pragma unroll
    for (int i = 0; i < 4; i++) {
        afr[0][i] = *(const short8*)&lA[aoff[i]];
        bfr[0][i] = *(const short8*)&lB[boff[i]];
    }

#pragma unroll
    for (int it = 0; it < NITER; ++it) {
        const int cs = it & 1;          // compile-time under full unroll
        const int ns = cs ^ 1;

        if (it == 0) {
            // tile 1 landed; tile 2's 4 loads stay in flight
            asm volatile("s_waitcnt vmcnt(4)\n\ts_barrier" ::: "memory");
        } else if (it < NITER - 1) {
            // tile it+1 landed (it was the only outstanding group)
            asm volatile("s_waitcnt vmcnt(0)\n\ts_barrier" ::: "memory");
        }
        // it == NITER-1: no LDS activity left; no barrier needed

        if (it >= 1 && it + 2 < NITER) {
            // stage tile it+2 into the buffer that held tile it-1 (reads sealed)
            const int nb = (it + 2) % 3;
            const int nk = (it + 2) * BK;
#pragma unroll
            for (int i = 0; i < 2; i++) {
                gll16(gA[i] + nk, lA + nb * LA_N + dAB[i]);
                gll16(gB[i] + nk, lB + nb * LB_N + dAB[i]);
            }
        }

        if (it + 1 < NITER) {
            const u16* ca = lA + ((it + 1) % 3) * LA_N;
            const u16* cb = lB + ((it + 1) % 3) * LB_N;
#pragma unroll
            for (int i = 0; i < 4; i++) {
                afr[ns][i] = *(const short8*)&ca[aoff[i]];
                bfr[ns][i] = *(const short8*)&cb[boff[i]];
            }
            // wait only the OLD 8 reads (frags[it]); the 8 just-issued stay in flight
            asm volatile("s_waitcnt lgkmcnt(8)" ::: "memory");
        } else {
            asm volatile("s_waitcnt lgkmcnt(0)" ::: "memory");
        }
        __builtin_amdgcn_sched_barrier(0);   // rule 18: pin MFMAs below the lgkm wait

        __builtin_amdgcn_s_setprio(1);
#pragma unroll
        for (int i = 0; i < 4; i++)
#pragma unroll
            for (int nf = 0; nf < 4; nf++)
                acc[i][nf] = __builtin_amdgcn_mfma_f32_16x16x32_bf16(
                    afr[cs][i], bfr[cs][nf], acc[i][nf], 0, 0, 0);
        __builtin_amdgcn_s_setprio(0);
    }

    // epilogue: out[tok][h] += acc*w + b (fp32 atomics; K-split + slot-pair accumulate)
#pragma unroll
    for (int mf = 0; mf < 4; mf++) {
#pragma unroll
        for (int r = 0; r < 4; r++) {
            const int m_local = wm + mf * 16 + fq * 4 + r;
            if (tile_m + m_local < cnt) {
                const int tok = toks[m_local];
                const float w = wgt[m_local], b = bia[m_local];
                float* op = out + (size_t)tok * HDIM;
#pragma unroll
                for (int nf = 0; nf < 4; nf++) {
                    const int h = tn + wn + nf * 16 + fm;
                    atomicAdd(op + h, acc[mf][nf][r] * w + b);
                }
            }
        }
    }
}

extern "C" void kernel_launch(void* const* d_in, const int* in_sizes, int n_in,
                              void* d_out, int out_size, void* d_ws, size_t ws_size,
                              hipStream_t stream) {
    const float* x  = (const float*)d_in[0];   // [4,2048,1024]
    const float* rw = (const float*)d_in[1];   // [8,1024]
    const float* ew = (const float*)d_in[2];   // [8,1024,1024]
    float* out = (float*)d_out;

    char* ws = (char*)d_ws;
    u16*    x_bf   = (u16*)ws;                          // 16 MiB
    u16*    w_bf   = (u16*)(ws + 16777216);             // 16 MiB
    float*  wt0    = (float*)(ws + 67108864);           // 32 KiB
    float*  wt1    = (float*)(ws + 67141632);           // 32 KiB
    float*  biasv  = (float*)(ws + 67174400);           // 32 KiB
    int*    sel    = (int*)(ws + 67207168);             // 32 KiB
    int*    lists  = (int*)(ws + 67239936);             // 256 KiB
    int*    ctrl   = (int*)(ws + 67502080);             // 544 B: counts[8*16] + done
    int*    tmap   = (int*)(ws + 67502720);             // 544 B

    prep<<<WBLK + RBLK, 256, 0, stream>>>(x, rw, ew, x_bf, w_bf, wt0, wt1, biasv, sel, ctrl, out);
    build_lists<<<NTOK / 256, 256, 0, stream>>>(sel, lists, ctrl, tmap);
    moe_gemm<<<dim3(MAXT, HDIM / TN, KSPL), 256, 0, stream>>>(
        x_bf, w_bf, lists, ctrl, tmap, wt0, wt1, biasv, out);
}

// Round 7
// 199.106 us; speedup vs baseline: 1.2769x; 1.2769x over previous
//
#include <hip/hip_runtime.h>
#include <hip/hip_fp16.h>
#include <cstdint>

typedef unsigned short u16;
typedef __attribute__((ext_vector_type(8))) short short8;
typedef __attribute__((ext_vector_type(4))) float float4v;

#define NTOK 8192
#define HDIM 1024
#define NEXP 8
#define TM 128
#define TN 128
#define BK 32
#define LA_N (TM * BK)           // one A buffer: 4096 u16 = 8 KB
#define LB_N (TN * BK)
#define MAXT 136   // max m-tiles over all experts: 16384/128 + 8 rounding partials
#define WBLK 8192  // prep: W-transpose blocks (32 x 32 x 8)
#define RBLK 2048  // prep: router blocks (4 tokens each)
#define SLOT_ELEMS ((size_t)NTOK * HDIM)   // one stage slot: 8M halfs = 16 MiB

__device__ __forceinline__ u16 f2bf(float f) {
    union { float f; uint32_t u; } v; v.f = f;
    uint32_t u = v.u;
    return (u16)((u + 0x7FFFu + ((u >> 16) & 1u)) >> 16);
}

// async global->LDS, 16B per lane; LDS dest = wave-uniform base + lane*16
__device__ __forceinline__ void gll16(const u16* g, u16* l) {
    __builtin_amdgcn_global_load_lds(
        (const __attribute__((address_space(1))) uint32_t*)g,
        (__attribute__((address_space(3))) uint32_t*)l,
        16, 0, 0);
}

// ---------------- fused prep: W transpose+quantize AND router AND ctrl zeroing ---------
__global__ __launch_bounds__(256) void prep(const float* __restrict__ x,
                                            const float* __restrict__ rw,
                                            const float* __restrict__ ew,
                                            u16* __restrict__ x_bf,
                                            u16* __restrict__ w_bf,
                                            float* __restrict__ wt0,
                                            float* __restrict__ wt1,
                                            float* __restrict__ biasv,
                                            int* __restrict__ sel,
                                            int* __restrict__ ctrl) {
    if (blockIdx.x == 0 && threadIdx.x < 132) ctrl[threadIdx.x] = 0;  // counts[8x16] + done

    if (blockIdx.x < WBLK) {
        __shared__ float tile[32][33];
        const int bid = blockIdx.x;
        const int e  = bid >> 10;
        const int k0 = (bid & 31) * 32;
        const int n0 = ((bid >> 5) & 31) * 32;
        const int r = threadIdx.x >> 3;        // 0..31
        const int c = (threadIdx.x & 7) * 4;   // 0,4,...,28
        const float4 v = *(const float4*)(ew + ((size_t)e << 20) + (size_t)(k0 + r) * HDIM + n0 + c);
        tile[r][c] = v.x; tile[r][c+1] = v.y; tile[r][c+2] = v.z; tile[r][c+3] = v.w;
        __syncthreads();
        ushort4 o;
        o.x = f2bf(tile[c][r]); o.y = f2bf(tile[c+1][r]);
        o.z = f2bf(tile[c+2][r]); o.w = f2bf(tile[c+3][r]);
        *(ushort4*)(w_bf + ((size_t)e << 20) + (size_t)(n0 + r) * HDIM + k0 + c) = o;
    } else {
        const int wv = threadIdx.x >> 6;
        const int l  = threadIdx.x & 63;
        const int n  = (blockIdx.x - WBLK) * 4 + wv;  // one wave per token
        const float4* xr = (const float4*)(x + (size_t)n * HDIM);
        ushort4* xo = (ushort4*)(x_bf + (size_t)n * HDIM);

        float4 xv[4];
#pragma unroll
        for (int t = 0; t < 4; t++) {
            xv[t] = xr[t * 64 + l];
            ushort4 p;
            p.x = f2bf(xv[t].x); p.y = f2bf(xv[t].y);
            p.z = f2bf(xv[t].z); p.w = f2bf(xv[t].w);
            xo[t * 64 + l] = p;
        }

        float logits[NEXP];
#pragma unroll
        for (int e = 0; e < NEXP; e++) {
            const float4* rwe = (const float4*)(rw + e * HDIM);
            float acc = 0.f;
#pragma unroll
            for (int t = 0; t < 4; t++) {
                const float4 r = rwe[t * 64 + l];
                acc += xv[t].x * r.x + xv[t].y * r.y + xv[t].z * r.z + xv[t].w * r.w;
            }
#pragma unroll
            for (int s = 32; s > 0; s >>= 1) acc += __shfl_xor(acc, s, 64);
            logits[e] = acc;
        }

        if (l == 0) {
            float mx = logits[0];
#pragma unroll
            for (int e = 1; e < NEXP; e++) mx = fmaxf(mx, logits[e]);
            float p[NEXP]; float sum = 0.f;
#pragma unroll
            for (int e = 0; e < NEXP; e++) { p[e] = expf(logits[e] - mx); sum += p[e]; }
            const float inv = 1.f / sum;
#pragma unroll
            for (int e = 0; e < NEXP; e++) p[e] *= inv;
            int e0 = 0;
#pragma unroll
            for (int e = 1; e < NEXP; e++) if (p[e] > p[e0]) e0 = e;  // ties -> lowest idx
            int e1 = (e0 == 0) ? 1 : 0;
#pragma unroll
            for (int e = 0; e < NEXP; e++) if (e != e0 && p[e] > p[e1]) e1 = e;
            const float p0 = p[e0], p1 = p[e1];
            const float wsum = p0 + p1 + 1e-6f;
            const float w0 = p0 / wsum, w1 = p1 / wsum;
            wt0[n] = w0; wt1[n] = w1;
            biasv[n] = w0 * p0 + w1 * p1;
            sel[n] = e0 | (e1 << 8);
        }
    }
}

// ---------------- list build + fused tile planning (last block plans) ------------------
__global__ __launch_bounds__(256) void build_lists(const int* __restrict__ sel,
                                                   int* __restrict__ lists,
                                                   int* __restrict__ ctrl,
                                                   int* __restrict__ tmap) {
    const int n  = blockIdx.x * 256 + threadIdx.x;
    const int wv = threadIdx.x >> 6;
    const int l  = threadIdx.x & 63;
    const int s  = sel[n];
    const int e0 = s & 0xFF, e1 = s >> 8;
    __shared__ int wcnt[NEXP][4];
    __shared__ int ebase[NEXP];
    int pf0 = 0, pf1 = 0;
    const unsigned long long ltmask = (1ULL << l) - 1ULL;
#pragma unroll
    for (int e = 0; e < NEXP; e++) {
        const int slot = (e0 == e) ? 0 : ((e1 == e) ? 1 : -1);
        const unsigned long long bal = __ballot(slot >= 0);
        const int pf = __popcll(bal & ltmask);
        if (slot == 0) pf0 = pf;
        if (slot == 1) pf1 = pf;
        if (l == 0) wcnt[e][wv] = __popcll(bal);
    }
    __syncthreads();
    if (threadIdx.x < NEXP) {
        const int e = threadIdx.x;
        const int tot = wcnt[e][0] + wcnt[e][1] + wcnt[e][2] + wcnt[e][3];
        ebase[e] = atomicAdd(&ctrl[e * 16], tot);   // counters 64B apart
    }
    __syncthreads();
    int off0 = ebase[e0], off1 = ebase[e1];
#pragma unroll
    for (int i = 0; i < 4; i++) {
        off0 += (i < wv) ? wcnt[e0][i] : 0;
        off1 += (i < wv) ? wcnt[e1][i] : 0;
    }
    lists[e0 * NTOK + off0 + pf0] = n;              // slot 0
    lists[e1 * NTOK + off1 + pf1] = n | 0x10000;    // slot 1

    // ---- last block to finish plans the dense tile map ----
    __shared__ int lastflag;
    __threadfence();
    if (threadIdx.x == 0) lastflag = (atomicAdd(&ctrl[128], 1) == (int)gridDim.x - 1);
    __syncthreads();
    if (lastflag) {
        __shared__ int tbase[NEXP + 1];
        if (threadIdx.x == 0) {
            int acc = 0;
            for (int e = 0; e < NEXP; e++) {
                tbase[e] = acc;
                acc += (atomicAdd(&ctrl[e * 16], 0) + TM - 1) / TM;  // device-scope read
            }
            tbase[NEXP] = acc;
        }
        __syncthreads();
        for (int i = threadIdx.x; i < MAXT; i += 256) {
            int v = -1;
#pragma unroll
            for (int e = 0; e < NEXP; e++)
                if (i >= tbase[e] && i < tbase[e + 1]) v = (e << 16) | (i - tbase[e]);
            tmap[i] = v;
        }
    }
}

// ------- grouped GEMM: 128x128, 4 waves of 64x64, R3 reg-dbuf pipeline ----------------
// template<KS>: K-split factor via blockIdx.z. KS=1 reproduces the proven R3 kernel
// byte-for-byte; KS=2 halves per-block K (NITER=16) and writes fp16 PARTIAL sums to
// stage slot (z*2 + expert_slot) -- plain stores, no atomics (R6's atomic lesson).
// Packing: KS=2 -> 2192 blocks over 768 resident slots = 0.95 vs R3's 0.71.
// 3 blocks/CU (LDS 50 KB, __launch_bounds__(256,3)). Counted lgkmcnt(8) reg-dbuf;
// sched_barrier after waits (rule 18); full unroll keeps indices compile-time.
template<int KS>
__global__ __launch_bounds__(256, 3) void moe_gemm(const u16* __restrict__ x_bf,
                                                   const u16* __restrict__ wt_bf,
                                                   const int* __restrict__ lists,
                                                   const int* __restrict__ ctrl,
                                                   const int* __restrict__ tmap,
                                                   const float* __restrict__ wt0,
                                                   const float* __restrict__ wt1,
                                                   const float* __restrict__ biasv,
                                                   __half* __restrict__ stage) {
    constexpr int NIT_ = (HDIM / BK) / KS;       // 32 (KS=1) or 16 (KS=2)
    const int ent = tmap[blockIdx.x];
    if (ent < 0) return;
    const int e = ent >> 16;
    const int tile_m = (ent & 0xFFFF) * TM;
    const int cnt = ctrl[e * 16];
    const int tn = blockIdx.y * TN;
    const int kz = blockIdx.z * (HDIM / KS);     // u16 element offset into K

    __shared__ u16 lA[3 * LA_N];   // 24 KB
    __shared__ u16 lB[3 * LB_N];   // 24 KB
    __shared__ int   toks[TM];
    __shared__ float wgt[TM];
    __shared__ float bia[TM];
    __shared__ int   slt[TM];

    const int t  = threadIdx.x;
    const int wv = t >> 6;
    const int l  = t & 63;

    if (t < TM) {
        const int idx = tile_m + t;
        int tok = 0; float w = 0.f, b = 0.f; int sl = 0;
        if (idx < cnt) {
            const int entry = lists[e * NTOK + idx];
            tok = entry & 0xFFFF;
            sl = entry >> 16;
            w = sl ? wt1[tok] : wt0[tok];
            b = (sl || blockIdx.z) ? 0.f : biasv[tok];   // bias exactly once per token
        }
        toks[t] = tok; wgt[t] = w; bia[t] = b; slt[t] = sl;
    }
    __syncthreads();

    // staging: slot s (16B) -> row = s>>2, phys-chunk pc = s&3, logical chunk
    // c = pc ^ ((row>>1)&3). A: 512 slots (2 wave-loads/wave), B same.
    const u16* gA[2]; const u16* gB[2]; int dAB[2];
#pragma unroll
    for (int i = 0; i < 2; i++) {
        const int slot = (i * 4 + wv) * 64 + l;
        const int row  = slot >> 2;
        const int c    = (slot & 3) ^ ((row >> 1) & 3);
        gA[i] = x_bf + (size_t)toks[row] * HDIM + kz + c * 8;
        gB[i] = wt_bf + ((size_t)e << 20) + (size_t)(tn + row) * HDIM + kz + c * 8;
        dAB[i] = (i * 4 + wv) * 512;                 // wave-uniform u16 offset in buffer
    }

    // fragment read offsets (swizzled, loop-invariant); wave -> 64x64 at (wm, wn)
    const int wm = (wv & 1) * 64;
    const int wn = (wv >> 1) * 64;
    const int fm = l & 15;
    const int fq = l >> 4;     // 0..3 (k-chunk)
    int aoff[4], boff[4];
#pragma unroll
    for (int i = 0; i < 4; i++) {
        const int ra = wm + i * 16 + fm;
        const int rb = wn + i * 16 + fm;
        aoff[i] = ra * BK + ((fq ^ ((ra >> 1) & 3)) * 8);
        boff[i] = rb * BK + ((fq ^ ((rb >> 1) & 3)) * 8);
    }

    float4v acc[4][4];
#pragma unroll
    for (int i = 0; i < 4; i++)
#pragma unroll
        for (int j = 0; j < 4; j++) { float4v z = {0.f, 0.f, 0.f, 0.f}; acc[i][j] = z; }

    short8 afr[2][4], bfr[2][4];   // register double-buffer of fragments

    // prologue: stage tiles 0,1,2 into buffers 0,1,2 (12 loads in flight)
#pragma unroll
    for (int tk = 0; tk < 3; tk++) {
#pragma unroll
        for (int i = 0; i < 2; i++) {
            gll16(gA[i] + tk * BK, lA + tk * LA_N + dAB[i]);
            gll16(gB[i] + tk * BK, lB + tk * LB_N + dAB[i]);
        }
    }
    // tile 0 landed (8 younger loads stay in flight)
    asm volatile("s_waitcnt vmcnt(8)\n\ts_barrier" ::: "memory");
    // read frags[0] into set 0
#pragma unroll
    for (int i = 0; i < 4; i++) {
        afr[0][i] = *(const short8*)&lA[aoff[i]];
        bfr[0][i] = *(const short8*)&lB[boff[i]];
    }

#pragma unroll
    for (int it = 0; it < NIT_; ++it) {
        const int cs = it & 1;          // compile-time under full unroll
        const int ns = cs ^ 1;

        if (it == 0) {
            // tile 1 landed; tile 2's 4 loads stay in flight
            asm volatile("s_waitcnt vmcnt(4)\n\ts_barrier" ::: "memory");
        } else if (it < NIT_ - 1) {
            // tile it+1 landed (it was the only outstanding group)
            asm volatile("s_waitcnt vmcnt(0)\n\ts_barrier" ::: "memory");
        }
        // it == NIT_-1: no LDS activity left; no barrier needed

        if (it >= 1 && it + 2 < NIT_) {
            // stage tile it+2 into the buffer that held tile it-1 (reads sealed)
            const int nb = (it + 2) % 3;
            const int nk = (it + 2) * BK;
#pragma unroll
            for (int i = 0; i < 2; i++) {
                gll16(gA[i] + nk, lA + nb * LA_N + dAB[i]);
                gll16(gB[i] + nk, lB + nb * LB_N + dAB[i]);
            }
        }

        if (it + 1 < NIT_) {
            const u16* ca = lA + ((it + 1) % 3) * LA_N;
            const u16* cb = lB + ((it + 1) % 3) * LB_N;
#pragma unroll
            for (int i = 0; i < 4; i++) {
                afr[ns][i] = *(const short8*)&ca[aoff[i]];
                bfr[ns][i] = *(const short8*)&cb[boff[i]];
            }
            // wait only the OLD 8 reads (frags[it]); the 8 just-issued stay in flight
            asm volatile("s_waitcnt lgkmcnt(8)" ::: "memory");
        } else {
            asm volatile("s_waitcnt lgkmcnt(0)" ::: "memory");
        }
        __builtin_amdgcn_sched_barrier(0);   // rule 18: pin MFMAs below the lgkm wait

        __builtin_amdgcn_s_setprio(1);
#pragma unroll
        for (int i = 0; i < 4; i++)
#pragma unroll
            for (int nf = 0; nf < 4; nf++)
                acc[i][nf] = __builtin_amdgcn_mfma_f32_16x16x32_bf16(
                    afr[cs][i], bfr[cs][nf], acc[i][nf], 0, 0, 0);
        __builtin_amdgcn_s_setprio(0);
    }

    // epilogue: stage[z*2+slot][tok][h] = fp16(acc*w + b) -- plain stores, race-free
    const size_t zbase = (size_t)blockIdx.z * 2 * SLOT_ELEMS;
#pragma unroll
    for (int mf = 0; mf < 4; mf++) {
#pragma unroll
        for (int r = 0; r < 4; r++) {
            const int m_local = wm + mf * 16 + fq * 4 + r;
            if (tile_m + m_local < cnt) {
                const int tok = toks[m_local];
                const float w = wgt[m_local], b = bia[m_local];
                __half* sp = stage + zbase + (slt[m_local] ? SLOT_ELEMS : 0)
                           + (size_t)tok * HDIM;
#pragma unroll
                for (int nf = 0; nf < 4; nf++) {
                    const int h = tn + wn + nf * 16 + fm;
                    sp[h] = __float2half(acc[mf][nf][r] * w + b);
                }
            }
        }
    }
}

// ---------------- combine: out = sum of NS stage slots (fully coalesced) ---------------
template<int NS>
__global__ __launch_bounds__(256) void combine(const __half* __restrict__ st,
                                               float* __restrict__ out) {
    const size_t idx = ((size_t)blockIdx.x * 256 + threadIdx.x) * 8;
    float o[8];
#pragma unroll
    for (int j = 0; j < 8; j++) o[j] = 0.f;
#pragma unroll
    for (int s = 0; s < NS; s++) {
        union { uint4 v; __half h[8]; } a;
        a.v = *(const uint4*)(st + s * SLOT_ELEMS + idx);
#pragma unroll
        for (int j = 0; j < 8; j++) o[j] += __half2float(a.h[j]);
    }
    float4 o0, o1;
    o0.x = o[0]; o0.y = o[1]; o0.z = o[2]; o0.w = o[3];
    o1.x = o[4]; o1.y = o[5]; o1.z = o[6]; o1.w = o[7];
    *(float4*)(out + idx)     = o0;
    *(float4*)(out + idx + 4) = o1;
}

extern "C" void kernel_launch(void* const* d_in, const int* in_sizes, int n_in,
                              void* d_out, int out_size, void* d_ws, size_t ws_size,
                              hipStream_t stream) {
    const float* x  = (const float*)d_in[0];   // [4,2048,1024]
    const float* rw = (const float*)d_in[1];   // [8,1024]
    const float* ew = (const float*)d_in[2];   // [8,1024,1024]
    float* out = (float*)d_out;

    char* ws = (char*)d_ws;
    u16*    x_bf  = (u16*)ws;                           // 16 MiB
    u16*    w_bf  = (u16*)(ws + 16777216);              // 16 MiB
    __half* stage = (__half*)(ws + 33554432);           // 2 or 4 x 16 MiB slots

    // K-split x2 needs 4 stage slots (ends at ~96.4 MiB); fallback (2 slots) ends at
    // 67,503,264 bytes == exactly the session-0-proven workspace bound.
    const bool split = ws_size >= 101057696ull;
    char* smalls = ws + 33554432 + (split ? 4 : 2) * (SLOT_ELEMS * sizeof(__half));
    float* wt0   = (float*)(smalls);                    // 32 KiB
    float* wt1   = (float*)(smalls + 32768);            // 32 KiB
    float* biasv = (float*)(smalls + 65536);            // 32 KiB
    int*   sel   = (int*)(smalls + 98304);              // 32 KiB
    int*   lists = (int*)(smalls + 131072);             // 256 KiB
    int*   ctrl  = (int*)(smalls + 393216);             // 528 B (pad to 640)
    int*   tmap  = (int*)(smalls + 393856);             // 544 B

    prep<<<WBLK + RBLK, 256, 0, stream>>>(x, rw, ew, x_bf, w_bf, wt0, wt1, biasv, sel, ctrl);
    build_lists<<<NTOK / 256, 256, 0, stream>>>(sel, lists, ctrl, tmap);
    if (split) {
        moe_gemm<2><<<dim3(MAXT, HDIM / TN, 2), 256, 0, stream>>>(
            x_bf, w_bf, lists, ctrl, tmap, wt0, wt1, biasv, stage);
        combine<4><<<(NTOK * HDIM) / (256 * 8), 256, 0, stream>>>(stage, out);
    } else {
        moe_gemm<1><<<dim3(MAXT, HDIM / TN, 1), 256, 0, stream>>>(
            x_bf, w_bf, lists, ctrl, tmap, wt0, wt1, biasv, stage);
        combine<2><<<(NTOK * HDIM) / (256 * 8), 256, 0, stream>>>(stage, out);
    }
}

// Round 8
// 195.071 us; speedup vs baseline: 1.3033x; 1.0207x over previous
//
#include <hip/hip_runtime.h>
#include <hip/hip_fp16.h>
#include <cstdint>

typedef unsigned short u16;
typedef __attribute__((ext_vector_type(8))) short short8;
typedef __attribute__((ext_vector_type(4))) float float4v;

#define NTOK 8192
#define HDIM 1024
#define NEXP 8
#define TM 128
#define TN 128
#define BK 32
#define NITER (HDIM / BK)        // 32
#define LA_N (TM * BK)           // one A buffer: 4096 u16 = 8 KB
#define LB_N (TN * BK)
#define MAXT 136   // max m-tiles over all experts: 16384/128 + 8 rounding partials
#define WBLK 2048  // prep: W-transpose blocks (64 x 64 tiles x 8 experts)
#define RBLK 2048  // prep: router blocks (4 tokens each)

__device__ __forceinline__ u16 f2bf(float f) {
    union { float f; uint32_t u; } v; v.f = f;
    uint32_t u = v.u;
    return (u16)((u + 0x7FFFu + ((u >> 16) & 1u)) >> 16);
}

// async global->LDS, 16B per lane; LDS dest = wave-uniform base + lane*16
__device__ __forceinline__ void gll16(const u16* g, u16* l) {
    __builtin_amdgcn_global_load_lds(
        (const __attribute__((address_space(1))) uint32_t*)g,
        (__attribute__((address_space(3))) uint32_t*)l,
        16, 0, 0);
}

// ---------------- fused prep: W transpose+quantize AND router AND ctrl zeroing ---------
// W-pass rewritten for DRAM locality: 64x64 tiles, 4 float4/thread -> 256B-contiguous
// reads per k-row, 128B-contiguous writes per n-row; 2048 blocks (was 8192 tiny ones).
__global__ __launch_bounds__(256) void prep(const float* __restrict__ x,
                                            const float* __restrict__ rw,
                                            const float* __restrict__ ew,
                                            u16* __restrict__ x_bf,
                                            u16* __restrict__ w_bf,
                                            float* __restrict__ wt0,
                                            float* __restrict__ wt1,
                                            float* __restrict__ biasv,
                                            int* __restrict__ sel,
                                            int* __restrict__ ctrl) {
    if (blockIdx.x == 0 && threadIdx.x < 132) ctrl[threadIdx.x] = 0;  // counts[8x16] + done

    if (blockIdx.x < WBLK) {
        __shared__ float tile[64][65];       // 16.64 KB; +1 pad, 2-way aliasing = free
        const int bid = blockIdx.x;
        const int e  = bid >> 8;                   // 8 experts x 256 tiles
        const int k0 = ((bid >> 4) & 15) * 64;
        const int n0 = (bid & 15) * 64;
        const int kr = threadIdx.x >> 2;           // 0..63
        const int ng = (threadIdx.x & 3) * 16;     // 0,16,32,48
        const float* src = ew + ((size_t)e << 20) + (size_t)(k0 + kr) * HDIM + n0 + ng;
#pragma unroll
        for (int j = 0; j < 4; j++) {
            const float4 v = *(const float4*)(src + 4 * j);
            tile[kr][ng + 4*j]     = v.x;
            tile[kr][ng + 4*j + 1] = v.y;
            tile[kr][ng + 4*j + 2] = v.z;
            tile[kr][ng + 4*j + 3] = v.w;
        }
        __syncthreads();
        const int nr = threadIdx.x >> 2;           // 0..63
        const int kg = (threadIdx.x & 3) * 16;
        u16* dst = w_bf + ((size_t)e << 20) + (size_t)(n0 + nr) * HDIM + k0 + kg;
#pragma unroll
        for (int j = 0; j < 4; j++) {
            ushort4 o;
            o.x = f2bf(tile[kg + 4*j][nr]);
            o.y = f2bf(tile[kg + 4*j + 1][nr]);
            o.z = f2bf(tile[kg + 4*j + 2][nr]);
            o.w = f2bf(tile[kg + 4*j + 3][nr]);
            *(ushort4*)(dst + 4 * j) = o;
        }
    } else {
        const int wv = threadIdx.x >> 6;
        const int l  = threadIdx.x & 63;
        const int n  = (blockIdx.x - WBLK) * 4 + wv;  // one wave per token
        const float4* xr = (const float4*)(x + (size_t)n * HDIM);
        ushort4* xo = (ushort4*)(x_bf + (size_t)n * HDIM);

        float4 xv[4];
#pragma unroll
        for (int t = 0; t < 4; t++) {
            xv[t] = xr[t * 64 + l];
            ushort4 p;
            p.x = f2bf(xv[t].x); p.y = f2bf(xv[t].y);
            p.z = f2bf(xv[t].z); p.w = f2bf(xv[t].w);
            xo[t * 64 + l] = p;
        }

        float logits[NEXP];
#pragma unroll
        for (int e = 0; e < NEXP; e++) {
            const float4* rwe = (const float4*)(rw + e * HDIM);
            float acc = 0.f;
#pragma unroll
            for (int t = 0; t < 4; t++) {
                const float4 r = rwe[t * 64 + l];
                acc += xv[t].x * r.x + xv[t].y * r.y + xv[t].z * r.z + xv[t].w * r.w;
            }
#pragma unroll
            for (int s = 32; s > 0; s >>= 1) acc += __shfl_xor(acc, s, 64);
            logits[e] = acc;
        }

        if (l == 0) {
            float mx = logits[0];
#pragma unroll
            for (int e = 1; e < NEXP; e++) mx = fmaxf(mx, logits[e]);
            float p[NEXP]; float sum = 0.f;
#pragma unroll
            for (int e = 0; e < NEXP; e++) { p[e] = expf(logits[e] - mx); sum += p[e]; }
            const float inv = 1.f / sum;
#pragma unroll
            for (int e = 0; e < NEXP; e++) p[e] *= inv;
            int e0 = 0;
#pragma unroll
            for (int e = 1; e < NEXP; e++) if (p[e] > p[e0]) e0 = e;  // ties -> lowest idx
            int e1 = (e0 == 0) ? 1 : 0;
#pragma unroll
            for (int e = 0; e < NEXP; e++) if (e != e0 && p[e] > p[e1]) e1 = e;
            const float p0 = p[e0], p1 = p[e1];
            const float wsum = p0 + p1 + 1e-6f;
            const float w0 = p0 / wsum, w1 = p1 / wsum;
            wt0[n] = w0; wt1[n] = w1;
            biasv[n] = w0 * p0 + w1 * p1;
            sel[n] = e0 | (e1 << 8);
        }
    }
}

// ---------------- list build + fused tile planning (last block plans) ------------------
__global__ __launch_bounds__(256) void build_lists(const int* __restrict__ sel,
                                                   int* __restrict__ lists,
                                                   int* __restrict__ ctrl,
                                                   int* __restrict__ tmap) {
    const int n  = blockIdx.x * 256 + threadIdx.x;
    const int wv = threadIdx.x >> 6;
    const int l  = threadIdx.x & 63;
    const int s  = sel[n];
    const int e0 = s & 0xFF, e1 = s >> 8;
    __shared__ int wcnt[NEXP][4];
    __shared__ int ebase[NEXP];
    int pf0 = 0, pf1 = 0;
    const unsigned long long ltmask = (1ULL << l) - 1ULL;
#pragma unroll
    for (int e = 0; e < NEXP; e++) {
        const int slot = (e0 == e) ? 0 : ((e1 == e) ? 1 : -1);
        const unsigned long long bal = __ballot(slot >= 0);
        const int pf = __popcll(bal & ltmask);
        if (slot == 0) pf0 = pf;
        if (slot == 1) pf1 = pf;
        if (l == 0) wcnt[e][wv] = __popcll(bal);
    }
    __syncthreads();
    if (threadIdx.x < NEXP) {
        const int e = threadIdx.x;
        const int tot = wcnt[e][0] + wcnt[e][1] + wcnt[e][2] + wcnt[e][3];
        ebase[e] = atomicAdd(&ctrl[e * 16], tot);   // counters 64B apart
    }
    __syncthreads();
    int off0 = ebase[e0], off1 = ebase[e1];
#pragma unroll
    for (int i = 0; i < 4; i++) {
        off0 += (i < wv) ? wcnt[e0][i] : 0;
        off1 += (i < wv) ? wcnt[e1][i] : 0;
    }
    lists[e0 * NTOK + off0 + pf0] = n;              // slot 0
    lists[e1 * NTOK + off1 + pf1] = n | 0x10000;    // slot 1

    // ---- last block to finish plans the dense tile map ----
    __shared__ int lastflag;
    __threadfence();
    if (threadIdx.x == 0) lastflag = (atomicAdd(&ctrl[128], 1) == (int)gridDim.x - 1);
    __syncthreads();
    if (lastflag) {
        __shared__ int tbase[NEXP + 1];
        if (threadIdx.x == 0) {
            int acc = 0;
            for (int e = 0; e < NEXP; e++) {
                tbase[e] = acc;
                acc += (atomicAdd(&ctrl[e * 16], 0) + TM - 1) / TM;  // device-scope read
            }
            tbase[NEXP] = acc;
        }
        __syncthreads();
        for (int i = threadIdx.x; i < MAXT; i += 256) {
            int v = -1;
#pragma unroll
            for (int e = 0; e < NEXP; e++)
                if (i >= tbase[e] && i < tbase[e + 1]) v = (e << 16) | (i - tbase[e]);
            tmap[i] = v;
        }
    }
}

// ---------------- grouped GEMM: 128x128, 4 waves of 64x64, reg-dbuf pipeline ----------
// R3 exact (best measured: 64.5 us). 3 blocks/CU (LDS 50 KB, __launch_bounds__(256,3)).
// Register double-buffer of fragments; counted lgkmcnt(8) so MFMA never waits on the
// just-issued ds_reads; sched_barrier after waits (rule 18); full unroll keeps indices
// compile-time. Conflict-free XOR swizzle: 16B chunk pc = c ^ ((row>>1)&3), applied to
// the pre-swizzled GLOBAL source (linear LDS dest) and the ds_read address.
__global__ __launch_bounds__(256, 3) void moe_gemm(const u16* __restrict__ x_bf,
                                                   const u16* __restrict__ wt_bf,
                                                   const int* __restrict__ lists,
                                                   const int* __restrict__ ctrl,
                                                   const int* __restrict__ tmap,
                                                   const float* __restrict__ wt0,
                                                   const float* __restrict__ wt1,
                                                   const float* __restrict__ biasv,
                                                   __half* __restrict__ stage0,
                                                   __half* __restrict__ stage1) {
    const int ent = tmap[blockIdx.x];
    if (ent < 0) return;
    const int e = ent >> 16;
    const int tile_m = (ent & 0xFFFF) * TM;
    const int cnt = ctrl[e * 16];
    const int tn = blockIdx.y * TN;

    __shared__ u16 lA[3 * LA_N];   // 24 KB
    __shared__ u16 lB[3 * LB_N];   // 24 KB
    __shared__ int   toks[TM];
    __shared__ float wgt[TM];
    __shared__ float bia[TM];
    __shared__ int   slt[TM];

    const int t  = threadIdx.x;
    const int wv = t >> 6;
    const int l  = t & 63;

    if (t < TM) {
        const int idx = tile_m + t;
        int tok = 0; float w = 0.f, b = 0.f; int sl = 0;
        if (idx < cnt) {
            const int entry = lists[e * NTOK + idx];
            tok = entry & 0xFFFF;
            sl = entry >> 16;
            w = sl ? wt1[tok] : wt0[tok];
            b = sl ? 0.f : biasv[tok];
        }
        toks[t] = tok; wgt[t] = w; bia[t] = b; slt[t] = sl;
    }
    __syncthreads();

    // staging: slot s (16B) -> row = s>>2, phys-chunk pc = s&3, logical chunk
    // c = pc ^ ((row>>1)&3). A: 512 slots (2 wave-loads/wave), B same.
    const u16* gA[2]; const u16* gB[2]; int dAB[2];
#pragma unroll
    for (int i = 0; i < 2; i++) {
        const int slot = (i * 4 + wv) * 64 + l;
        const int row  = slot >> 2;
        const int c    = (slot & 3) ^ ((row >> 1) & 3);
        gA[i] = x_bf + (size_t)toks[row] * HDIM + c * 8;
        gB[i] = wt_bf + ((size_t)e << 20) + (size_t)(tn + row) * HDIM + c * 8;
        dAB[i] = (i * 4 + wv) * 512;                 // wave-uniform u16 offset in buffer
    }

    // fragment read offsets (swizzled, loop-invariant); wave -> 64x64 at (wm, wn)
    const int wm = (wv & 1) * 64;
    const int wn = (wv >> 1) * 64;
    const int fm = l & 15;
    const int fq = l >> 4;     // 0..3 (k-chunk)
    int aoff[4], boff[4];
#pragma unroll
    for (int i = 0; i < 4; i++) {
        const int ra = wm + i * 16 + fm;
        const int rb = wn + i * 16 + fm;
        aoff[i] = ra * BK + ((fq ^ ((ra >> 1) & 3)) * 8);
        boff[i] = rb * BK + ((fq ^ ((rb >> 1) & 3)) * 8);
    }

    float4v acc[4][4];
#pragma unroll
    for (int i = 0; i < 4; i++)
#pragma unroll
        for (int j = 0; j < 4; j++) { float4v z = {0.f, 0.f, 0.f, 0.f}; acc[i][j] = z; }

    short8 afr[2][4], bfr[2][4];   // register double-buffer of fragments

    // prologue: stage tiles 0,1,2 into buffers 0,1,2 (12 loads in flight)
#pragma unroll
    for (int tk = 0; tk < 3; tk++) {
#pragma unroll
        for (int i = 0; i < 2; i++) {
            gll16(gA[i] + tk * BK, lA + tk * LA_N + dAB[i]);
            gll16(gB[i] + tk * BK, lB + tk * LB_N + dAB[i]);
        }
    }
    // tile 0 landed (8 younger loads stay in flight)
    asm volatile("s_waitcnt vmcnt(8)\n\ts_barrier" ::: "memory");
    // read frags[0] into set 0
#pragma unroll
    for (int i = 0; i < 4; i++) {
        afr[0][i] = *(const short8*)&lA[aoff[i]];
        bfr[0][i] = *(const short8*)&lB[boff[i]];
    }

#pragma unroll
    for (int it = 0; it < NITER; ++it) {
        const int cs = it & 1;          // compile-time under full unroll
        const int ns = cs ^ 1;

        if (it == 0) {
            // tile 1 landed; tile 2's 4 loads stay in flight
            asm volatile("s_waitcnt vmcnt(4)\n\ts_barrier" ::: "memory");
        } else if (it < NITER - 1) {
            // tile it+1 landed (it was the only outstanding group)
            asm volatile("s_waitcnt vmcnt(0)\n\ts_barrier" ::: "memory");
        }
        // it == NITER-1: no LDS activity left; no barrier needed

        if (it >= 1 && it + 2 < NITER) {
            // stage tile it+2 into the buffer that held tile it-1 (reads sealed)
            const int nb = (it + 2) % 3;
            const int nk = (it + 2) * BK;
#pragma unroll
            for (int i = 0; i < 2; i++) {
                gll16(gA[i] + nk, lA + nb * LA_N + dAB[i]);
                gll16(gB[i] + nk, lB + nb * LB_N + dAB[i]);
            }
        }

        if (it + 1 < NITER) {
            const u16* ca = lA + ((it + 1) % 3) * LA_N;
            const u16* cb = lB + ((it + 1) % 3) * LB_N;
#pragma unroll
            for (int i = 0; i < 4; i++) {
                afr[ns][i] = *(const short8*)&ca[aoff[i]];
                bfr[ns][i] = *(const short8*)&cb[boff[i]];
            }
            // wait only the OLD 8 reads (frags[it]); the 8 just-issued stay in flight
            asm volatile("s_waitcnt lgkmcnt(8)" ::: "memory");
        } else {
            asm volatile("s_waitcnt lgkmcnt(0)" ::: "memory");
        }
        __builtin_amdgcn_sched_barrier(0);   // rule 18: pin MFMAs below the lgkm wait

        __builtin_amdgcn_s_setprio(1);
#pragma unroll
        for (int i = 0; i < 4; i++)
#pragma unroll
            for (int nf = 0; nf < 4; nf++)
                acc[i][nf] = __builtin_amdgcn_mfma_f32_16x16x32_bf16(
                    afr[cs][i], bfr[cs][nf], acc[i][nf], 0, 0, 0);
        __builtin_amdgcn_s_setprio(0);
    }

    // epilogue: stage[slot][tok][h] = fp16(acc*w + b)  -- plain stores, race-free
#pragma unroll
    for (int mf = 0; mf < 4; mf++) {
#pragma unroll
        for (int r = 0; r < 4; r++) {
            const int m_local = wm + mf * 16 + fq * 4 + r;
            if (tile_m + m_local < cnt) {
                const int tok = toks[m_local];
                const float w = wgt[m_local], b = bia[m_local];
                __half* sp = (slt[m_local] ? stage1 : stage0) + (size_t)tok * HDIM;
#pragma unroll
                for (int nf = 0; nf < 4; nf++) {
                    const int h = tn + wn + nf * 16 + fm;
                    sp[h] = __float2half(acc[mf][nf][r] * w + b);
                }
            }
        }
    }
}

// ---------------- combine: out = stage0 + stage1 (fully coalesced) ----------------
__global__ __launch_bounds__(256) void combine(const __half* __restrict__ s0,
                                               const __half* __restrict__ s1,
                                               float* __restrict__ out) {
    const size_t idx = ((size_t)blockIdx.x * 256 + threadIdx.x) * 8;
    union { uint4 v; __half h[8]; } a, b;
    a.v = *(const uint4*)(s0 + idx);
    b.v = *(const uint4*)(s1 + idx);
    float4 o0, o1;
    o0.x = __half2float(a.h[0]) + __half2float(b.h[0]);
    o0.y = __half2float(a.h[1]) + __half2float(b.h[1]);
    o0.z = __half2float(a.h[2]) + __half2float(b.h[2]);
    o0.w = __half2float(a.h[3]) + __half2float(b.h[3]);
    o1.x = __half2float(a.h[4]) + __half2float(b.h[4]);
    o1.y = __half2float(a.h[5]) + __half2float(b.h[5]);
    o1.z = __half2float(a.h[6]) + __half2float(b.h[6]);
    o1.w = __half2float(a.h[7]) + __half2float(b.h[7]);
    *(float4*)(out + idx)     = o0;
    *(float4*)(out + idx + 4) = o1;
}

extern "C" void kernel_launch(void* const* d_in, const int* in_sizes, int n_in,
                              void* d_out, int out_size, void* d_ws, size_t ws_size,
                              hipStream_t stream) {
    const float* x  = (const float*)d_in[0];   // [4,2048,1024]
    const float* rw = (const float*)d_in[1];   // [8,1024]
    const float* ew = (const float*)d_in[2];   // [8,1024,1024]
    float* out = (float*)d_out;

    char* ws = (char*)d_ws;
    u16*    x_bf   = (u16*)ws;                          // 16 MiB
    u16*    w_bf   = (u16*)(ws + 16777216);             // 16 MiB
    __half* stage0 = (__half*)(ws + 33554432);          // 16 MiB
    __half* stage1 = (__half*)(ws + 50331648);          // 16 MiB
    float*  wt0    = (float*)(ws + 67108864);           // 32 KiB
    float*  wt1    = (float*)(ws + 67141632);           // 32 KiB
    float*  biasv  = (float*)(ws + 67174400);           // 32 KiB
    int*    sel    = (int*)(ws + 67207168);             // 32 KiB
    int*    lists  = (int*)(ws + 67239936);             // 256 KiB
    int*    ctrl   = (int*)(ws + 67502080);             // 544 B: counts[8*16] + done
    int*    tmap   = (int*)(ws + 67502720);             // 544 B

    prep<<<WBLK + RBLK, 256, 0, stream>>>(x, rw, ew, x_bf, w_bf, wt0, wt1, biasv, sel, ctrl);
    build_lists<<<NTOK / 256, 256, 0, stream>>>(sel, lists, ctrl, tmap);
    moe_gemm<<<dim3(MAXT, HDIM / TN, 1), 256, 0, stream>>>(
        x_bf, w_bf, lists, ctrl, tmap, wt0, wt1, biasv, stage0, stage1);
    combine<<<(NTOK * HDIM) / (256 * 8), 256, 0, stream>>>(stage0, stage1, out);
}